// Round 11
// baseline (88.996 us; speedup 1.0000x reference)
//
#include <hip/hip_runtime.h>
#include <hip/hip_bf16.h>

typedef __bf16 bf16x8 __attribute__((ext_vector_type(8)));
typedef float  f32x4  __attribute__((ext_vector_type(4)));
typedef float  f32x16 __attribute__((ext_vector_type(16)));

constexpr int Bn = 8192, Dn = 64, On = 256;

// async global->LDS DMA: lds dst = wave-uniform base, HW adds lane*16
#define GLD16(g, l) __builtin_amdgcn_global_load_lds( \
    (const __attribute__((address_space(1))) void*)(g), \
    (__attribute__((address_space(3))) void*)(l), 16, 0, 0)

// ---- prep: bTsw[o] = A-image in EXACT read order: chunk((et*4+k)*64+lane) =
//      betaT[e = et*32+(lane&31)][d = (k*2+(lane>>5))*8 .. +7]  -> both the
//      GLD16 writes and the af ds_read_b128 are stride-1 (conflict-free).
//      ncpk[o][64] = -c_proj packed in 32x32 C-register order. ----
__global__ void k_prep(const float* __restrict__ betas, const float* __restrict__ centers,
                       __bf16* __restrict__ bTsw, float* __restrict__ ncpk) {
    __shared__ float s[64 * 65];                        // +1 pad transpose buffer
    const int o = blockIdx.x, tid = threadIdx.x;
    const float* bo = betas + (size_t)o * 4096;         // betas[o][d][e]
    for (int j = tid; j < 1024; j += 256) {
        int d = j >> 4, e4 = (j & 15) * 4;
        float4 v = ((const float4*)bo)[j];
        s[d * 65 + e4 + 0] = v.x; s[d * 65 + e4 + 1] = v.y;
        s[d * 65 + e4 + 2] = v.z; s[d * 65 + e4 + 3] = v.w;
    }
    __syncthreads();
    for (int p = tid; p < 4096; p += 256) {
        int chunk = p >> 3, j = p & 7;
        int ek = chunk >> 6, lane = chunk & 63;         // ek = et*4 + k
        int e = (ek >> 2) * 32 + (lane & 31);
        int d = ((ek & 3) * 2 + (lane >> 5)) * 8 + j;
        bTsw[(size_t)o * 4096 + p] = (__bf16)s[d * 65 + e];
    }
    // -cproj packed: [et][l5][reg] -> e-row = 32*et + 4*l5 + (reg&3) + 8*(reg>>2)
    if (tid < 64) {
        int et = tid >> 5, rem = tid & 31, l5 = rem >> 4, reg = rem & 15;
        int row = et * 32 + l5 * 4 + (reg & 3) + ((reg >> 2) << 3);
        float acc = 0.f;
        for (int d = 0; d < 64; ++d) acc += s[d * 65 + row] * centers[o * 64 + d];
        ncpk[o * 64 + tid] = -acc;
    }
}

// ---- main: block = 4 waves x 256 b, 8 o. 4 blocks/CU -> 4 waves/SIMD (the
//      R8-R10 bug was waves_per_eu(2,2) capping occupancy at 2). A-image
//      double-buffered + barrier-paced; fp32 cp C-init; deferred epilogue. ----
__global__ void __launch_bounds__(256, 4)
k_main(const float* __restrict__ x, const __bf16* __restrict__ bTsw,
       const float* __restrict__ ncpk, float* __restrict__ out) {
    __shared__ __align__(16) unsigned char smem[2 * 8192 + 2048];   // 18.4 KB
    __bf16* sA0 = (__bf16*)smem;
    __bf16* sA1 = (__bf16*)(smem + 8192);
    float*  sCp = (float*)(smem + 16384);               // 8 o x 64 packed -cp

    const int tid = threadIdx.x, wq = tid >> 6, lane = tid & 63;
    const int l31 = lane & 31, l5 = lane >> 5;
    const int bbase = blockIdx.x * 256;                 // x = b-strip (32)
    const int o0 = blockIdx.y * 8;                      // y = o-group (32); +32 id = same XCD

    sCp[tid]       = ncpk[o0 * 64 + tid];
    sCp[256 + tid] = ncpk[o0 * 64 + 256 + tid];

    // x-fragments from global (one-time), B-operand layout: 32 VGPR
    bf16x8 xf[2][4];                                    // [bt][kstep]
#pragma unroll
    for (int bt = 0; bt < 2; ++bt)
#pragma unroll
        for (int kk = 0; kk < 4; ++kk) {
            const float* xp = x + (size_t)(bbase + wq * 64 + bt * 32 + l31) * 64
                                + (kk * 2 + l5) * 8;
            float4 v0 = *(const float4*)xp, v1 = *(const float4*)(xp + 4);
            bf16x8 f;
            f[0] = (__bf16)v0.x; f[1] = (__bf16)v0.y; f[2] = (__bf16)v0.z; f[3] = (__bf16)v0.w;
            f[4] = (__bf16)v1.x; f[5] = (__bf16)v1.y; f[6] = (__bf16)v1.z; f[7] = (__bf16)v1.w;
            xf[bt][kk] = f;
        }

    // each wave DMAs its quarter (2 KB) of the 8 KB A-image
    auto prefetch = [&](int o, __bf16* buf) {
        const __bf16* g = bTsw + (size_t)o * 4096;
        GLD16(g + (size_t)(wq * 128 + lane) * 8,      buf + (wq * 128) * 8);
        GLD16(g + (size_t)(wq * 128 + 64 + lane) * 8, buf + (wq * 128 + 64) * 8);
    };

    float qd[8];                                        // lane's row-q per o
    prefetch(o0, sA0);
    __builtin_amdgcn_s_waitcnt(0x0f70);                 // vmcnt(0)
    __syncthreads();

#pragma unroll
    for (int oi = 0; oi < 8; ++oi) {
        __bf16* cur = (oi & 1) ? sA1 : sA0;
        if (oi < 7) prefetch(o0 + oi + 1, (oi & 1) ? sA0 : sA1);

        f32x4 qv[2] = {{0,0,0,0},{0,0,0,0}};
#pragma unroll
        for (int et = 0; et < 2; ++et) {
            f32x16 cpv;                                 // C-init = -cp (C-reg order, fp32)
#pragma unroll
            for (int r4 = 0; r4 < 4; ++r4)
                ((f32x4*)&cpv)[r4] = *(const f32x4*)(sCp + oi * 64 + et * 32 + l5 * 16 + r4 * 4);
            bf16x8 af[4];                               // stride-1 ds_read_b128
#pragma unroll
            for (int k = 0; k < 4; ++k)
                af[k] = *(const bf16x8*)(cur + (size_t)((et * 4 + k) * 64 + lane) * 8);
#pragma unroll
            for (int bt = 0; bt < 2; ++bt) {
                f32x16 acc = __builtin_amdgcn_mfma_f32_32x32x16_bf16(af[0], xf[bt][0], cpv, 0, 0, 0);
                acc = __builtin_amdgcn_mfma_f32_32x32x16_bf16(af[1], xf[bt][1], acc, 0, 0, 0);
                acc = __builtin_amdgcn_mfma_f32_32x32x16_bf16(af[2], xf[bt][2], acc, 0, 0, 0);
                acc = __builtin_amdgcn_mfma_f32_32x32x16_bf16(af[3], xf[bt][3], acc, 0, 0, 0);
                const f32x4* aq = (const f32x4*)&acc;   // packed v_pk_fma_f32 squaring
                qv[bt] += aq[0] * aq[0];
                qv[bt] += aq[1] * aq[1];
                qv[bt] += aq[2] * aq[2];
                qv[bt] += aq[3] * aq[3];
            }
        }
        float q0 = (qv[0][0] + qv[0][1]) + (qv[0][2] + qv[0][3]);
        float q1 = (qv[1][0] + qv[1][1]) + (qv[1][2] + qv[1][3]);
        q0 += __shfl_xor(q0, 32, 64);                   // merge l5 halves (full 64-e sum)
        q1 += __shfl_xor(q1, 32, 64);
        qd[oi] = l5 ? q1 : q0;                          // lane owns row l5*32 + l31

        __builtin_amdgcn_sched_barrier(0);
        __builtin_amdgcn_s_waitcnt(0x0f70);             // my prefetch landed long ago
        __syncthreads();                                // all quarters in; cur reads done
    }
    __syncthreads();                                    // A buffers dead; reuse as scratch

    // epilogue: rows padded to 12 floats (48 B: 16B-aligned b128 reads)
    float* scr = (float*)smem;                          // 256 rows x 12 floats = 12 KB
    {
        int r = wq * 64 + l5 * 32 + l31;                // lane's row
#pragma unroll
        for (int oi = 0; oi < 8; ++oi) scr[r * 12 + oi] = qd[oi];
    }
    __syncthreads();
    {
        const float* q8 = scr + tid * 12;               // thread = row
        f32x4 r0 = *(const f32x4*)q8, r1 = *(const f32x4*)(q8 + 4);
        f32x4 e0, e1;
#pragma unroll
        for (int j = 0; j < 4; ++j) { e0[j] = __expf(-r0[j]); e1[j] = __expf(-r1[j]); }
        float* op = out + (size_t)(bbase + tid) * 256 + o0;
        *(f32x4*)op       = e0;                         // 32 B burst per row
        *(f32x4*)(op + 4) = e1;
    }
}

extern "C" void kernel_launch(void* const* d_in, const int* in_sizes, int n_in,
                              void* d_out, int out_size, void* d_ws, size_t ws_size,
                              hipStream_t stream) {
    const float* x       = (const float*)d_in[0];   // [8192,64]
    const float* centers = (const float*)d_in[1];   // [256,1,64]
    const float* betas   = (const float*)d_in[2];   // [256,64,64]
    float* out = (float*)d_out;                     // [8192,256] fp32

    char* ws = (char*)d_ws;
    __bf16* bTsw = (__bf16*)ws;                     // 2 MB (read-order A-images)
    float*  ncpk = (float*)(ws + 2 * (1 << 20));    // 64 KB (packed -cproj)

    k_prep<<<dim3(On),                dim3(256), 0, stream>>>(betas, centers, bTsw, ncpk);
    k_main<<<dim3(Bn / 256, On / 8),  dim3(256), 0, stream>>>(x, bTsw, ncpk, out);
}